// Round 1
// baseline (673.990 us; speedup 1.0000x reference)
//
#include <hip/hip_runtime.h>
#include <cstdint>
#include <cstddef>

// Problem: out = x @ W + (x @ A) @ B ; second output = bias (passthrough)
//   x: [8192,4096] f32, W: [4096,4096] f32, bias: [4096] f32,
//   A: [4096,16] f32, B: [16,4096] f32
// Strategy: fold LoRA into the weight once (W_eff = W + A@B, stored transposed
// in bf16), cast x to bf16, then one big bf16 MFMA GEMM with fp32 accumulate.
// Workspace layout (needs 100,663,296 B):
//   [0, 67108864)              x_bf16  [8192][4096] bf16
//   [67108864, 100663296)      WeffT   [4096(n)][4096(k)] bf16 (K-contiguous)

#define SEQ  8192
#define DIN  4096
#define DOUT 4096
#define RANK 16

typedef __attribute__((ext_vector_type(8))) __bf16 bf16x8;     // MFMA A/B frag
typedef __attribute__((ext_vector_type(4))) float f32x4;       // MFMA C/D frag
typedef __attribute__((ext_vector_type(8))) unsigned short ushort8;

__device__ __forceinline__ unsigned short f32_to_bf16_rne(float f) {
  union { float f; unsigned int u; } cv;
  cv.f = f;
  unsigned int u = cv.u;
  u += 0x7FFFu + ((u >> 16) & 1u);   // round-to-nearest-even
  return (unsigned short)(u >> 16);
}

// ---------------- Kernel 1: x fp32 -> bf16 (+ bias passthrough) -------------
__global__ __launch_bounds__(256) void cast_x_kernel(
    const float* __restrict__ x, unsigned short* __restrict__ xb,
    const float* __restrict__ bias, float* __restrict__ bias_out) {
  const int tid = blockIdx.x * 256 + threadIdx.x;   // one thread = 8 floats
  const float4* x4 = (const float4*)x;
  float4 v0 = x4[(size_t)tid * 2 + 0];
  float4 v1 = x4[(size_t)tid * 2 + 1];
  ushort8 o;
  o[0] = f32_to_bf16_rne(v0.x); o[1] = f32_to_bf16_rne(v0.y);
  o[2] = f32_to_bf16_rne(v0.z); o[3] = f32_to_bf16_rne(v0.w);
  o[4] = f32_to_bf16_rne(v1.x); o[5] = f32_to_bf16_rne(v1.y);
  o[6] = f32_to_bf16_rne(v1.z); o[7] = f32_to_bf16_rne(v1.w);
  *(ushort8*)(xb + (size_t)tid * 8) = o;
  if (tid < DOUT) bias_out[tid] = bias[tid];
}

// ---------------- Kernel 2: WeffT[n][k] = bf16(W[k][n] + sum_r A[k][r]B[r][n])
// 64x64 tile; coalesced read of W (n fastest), LDS transpose (padded),
// coalesced bf16 write of the transposed tile (k fastest).
__global__ __launch_bounds__(256) void weff_kernel(
    const float* __restrict__ W, const float* __restrict__ A,
    const float* __restrict__ B, unsigned short* __restrict__ WT) {
  __shared__ float sB[RANK][64];
  __shared__ float sA[64][RANK];
  __shared__ unsigned short sT[64][65];   // [k][n], padded to break conflicts
  const int n0 = blockIdx.x * 64;
  const int k0 = blockIdx.y * 64;
  const int t = threadIdx.x;

  for (int idx = t; idx < RANK * 64; idx += 256) {
    int r = idx >> 6, c = idx & 63;
    sB[r][c] = B[(size_t)r * DOUT + n0 + c];
  }
  for (int idx = t; idx < 64 * RANK; idx += 256) {
    int i = idx >> 4, r = idx & 15;
    sA[i][r] = A[(size_t)(k0 + i) * RANK + r];
  }
  __syncthreads();

  const int c = t & 63;     // lane within wave
  const int sub = t >> 6;   // wave id 0..3
  #pragma unroll
  for (int p = 0; p < 16; ++p) {
    const int ki = p * 4 + sub;
    float acc = W[(size_t)(k0 + ki) * DOUT + n0 + c];
    #pragma unroll
    for (int r = 0; r < RANK; ++r) acc += sA[ki][r] * sB[r][c];
    sT[ki][c] = f32_to_bf16_rne(acc);
  }
  __syncthreads();
  #pragma unroll
  for (int p = 0; p < 16; ++p) {
    const int ni = p * 4 + sub;
    WT[(size_t)(n0 + ni) * DIN + k0 + c] = sT[c][ni];
  }
}

// ---------------- Kernel 3: C[m][n] = sum_k xb[m][k] * WT[n][k] (bf16 MFMA) --
// m97 structure: 128x128 tile, BK=32, 256 threads = 4 waves (2x2), each wave
// 4x4 tiles of v_mfma_f32_16x16x32_bf16. Staging via global_load_lds width 16.
#define BM 128
#define BN 128
#define BK 32

__global__ __launch_bounds__(256) void gemm_bt_kernel(
    const unsigned short* __restrict__ xb, const unsigned short* __restrict__ wt,
    float* __restrict__ out) {
  __shared__ unsigned short sA[BM * BK];  // [m][k], k contiguous (8 KB)
  __shared__ unsigned short sB[BN * BK];  // [n][k], k contiguous (8 KB)
  const int t = threadIdx.x;
  const int n0 = blockIdx.x * BN;
  const int m0 = blockIdx.y * BM;

  const int lane = t & 63;
  const int wv   = t >> 6;
  const int wr   = wv >> 1;     // wave row (0..1) -> 64 rows of C
  const int wc   = wv & 1;      // wave col (0..1) -> 64 cols of C
  const int quad = lane >> 4;   // 0..3
  const int lcol = lane & 15;

  // Staging: chunk c (0..511) = 16 B -> LDS byte c*16; row=c/4, 16B-col=c%4.
  // Wave-uniform base + lane*16 is exactly this layout (G16B contiguity).
  const int srow = t >> 2;
  const int scol = (t & 3) * 8;           // bf16 elements
  const unsigned short* gA0 = xb + (size_t)(m0 + srow) * DIN + scol;
  const unsigned short* gA1 = gA0 + (size_t)64 * DIN;
  const unsigned short* gB0 = wt + (size_t)(n0 + srow) * DIN + scol;
  const unsigned short* gB1 = gB0 + (size_t)64 * DIN;
  unsigned short* lA0 = (unsigned short*)sA + t * 8;
  unsigned short* lA1 = (unsigned short*)sA + (t + 256) * 8;
  unsigned short* lB0 = (unsigned short*)sB + t * 8;
  unsigned short* lB1 = (unsigned short*)sB + (t + 256) * 8;

  f32x4 acc[4][4] = {};

  // Per-wave fragment offsets (shorts). a: A[m=lcol][k=quad*8+j] per MFMA spec.
  const int aoff = (wr * 64 + lcol) * BK + quad * 8;
  const int boff = (wc * 64 + lcol) * BK + quad * 8;

  for (int kt = 0; kt < DIN; kt += BK) {
    __builtin_amdgcn_global_load_lds(
        (const __attribute__((address_space(1))) void*)(gA0 + kt),
        (__attribute__((address_space(3))) void*)lA0, 16, 0, 0);
    __builtin_amdgcn_global_load_lds(
        (const __attribute__((address_space(1))) void*)(gA1 + kt),
        (__attribute__((address_space(3))) void*)lA1, 16, 0, 0);
    __builtin_amdgcn_global_load_lds(
        (const __attribute__((address_space(1))) void*)(gB0 + kt),
        (__attribute__((address_space(3))) void*)lB0, 16, 0, 0);
    __builtin_amdgcn_global_load_lds(
        (const __attribute__((address_space(1))) void*)(gB1 + kt),
        (__attribute__((address_space(3))) void*)lB1, 16, 0, 0);
    __syncthreads();   // drains vmcnt(0) before barrier -> staging visible

    bf16x8 a[4], b[4];
    #pragma unroll
    for (int i = 0; i < 4; ++i)
      a[i] = *(const bf16x8*)((const unsigned short*)sA + aoff + i * 16 * BK);
    #pragma unroll
    for (int j = 0; j < 4; ++j)
      b[j] = *(const bf16x8*)((const unsigned short*)sB + boff + j * 16 * BK);

    #pragma unroll
    for (int i = 0; i < 4; ++i)
      #pragma unroll
      for (int j = 0; j < 4; ++j)
        acc[i][j] = __builtin_amdgcn_mfma_f32_16x16x32_bf16(a[i], b[j], acc[i][j], 0, 0, 0);
    __syncthreads();   // protect LDS from next iteration's staging
  }

  // Epilogue: C/D layout col=lane&15, row=(lane>>4)*4+reg  [measured m89/m91]
  const int row_base = m0 + wr * 64 + quad * 4;
  const int col_base = n0 + wc * 64 + lcol;
  #pragma unroll
  for (int i = 0; i < 4; ++i)
    #pragma unroll
    for (int j = 0; j < 4; ++j)
      #pragma unroll
      for (int r = 0; r < 4; ++r)
        out[(size_t)(row_base + i * 16 + r) * DOUT + (col_base + j * 16)] =
            acc[i][j][r];
}

extern "C" void kernel_launch(void* const* d_in, const int* in_sizes, int n_in,
                              void* d_out, int out_size, void* d_ws, size_t ws_size,
                              hipStream_t stream) {
  const float* x    = (const float*)d_in[0];
  const float* W    = (const float*)d_in[1];
  const float* bias = (const float*)d_in[2];
  const float* A    = (const float*)d_in[3];
  const float* B    = (const float*)d_in[4];
  float* out      = (float*)d_out;
  float* bias_out = out + (size_t)SEQ * DOUT;   // second output, concatenated

  unsigned short* xb = (unsigned short*)d_ws;                   // 67,108,864 B
  unsigned short* wt = xb + (size_t)SEQ * DIN;                  // 33,554,432 B

  // 1) cast x -> bf16, copy bias to output tail
  cast_x_kernel<<<(SEQ * DIN) / (256 * 8), 256, 0, stream>>>(x, xb, bias, bias_out);
  // 2) WeffT = (W + A@B)^T in bf16
  weff_kernel<<<dim3(DOUT / 64, DIN / 64), 256, 0, stream>>>(W, A, B, wt);
  // 3) big bf16 GEMM: out = x @ Weff
  gemm_bt_kernel<<<dim3(DOUT / BN, SEQ / BM), 256, 0, stream>>>(xb, wt, out);
}

// Round 2
// 664.780 us; speedup vs baseline: 1.0139x; 1.0139x over previous
//
#include <hip/hip_runtime.h>
#include <cstdint>
#include <cstddef>

// Problem: out = x @ W + (x @ A) @ B ; second output = bias (passthrough)
//   x: [8192,4096] f32, W: [4096,4096] f32, bias: [4096] f32,
//   A: [4096,16] f32, B: [16,4096] f32
// Strategy: fold LoRA into the weight once (W_eff = W + A@B, stored transposed
// in bf16), cast x to bf16, then one big bf16 MFMA GEMM with fp32 accumulate.
// R2: XOR-swizzled LDS chunk placement in the GEMM to kill the 8-way
// ds_read_b128 bank conflicts (3.35e7 conflict cycles in R1).
// Workspace layout (needs 100,663,296 B):
//   [0, 67108864)              x_bf16  [8192][4096] bf16
//   [67108864, 100663296)      WeffT   [4096(n)][4096(k)] bf16 (K-contiguous)

#define SEQ  8192
#define DIN  4096
#define DOUT 4096
#define RANK 16

typedef __attribute__((ext_vector_type(8))) __bf16 bf16x8;     // MFMA A/B frag
typedef __attribute__((ext_vector_type(4))) float f32x4;       // MFMA C/D frag
typedef __attribute__((ext_vector_type(8))) unsigned short ushort8;

__device__ __forceinline__ unsigned short f32_to_bf16_rne(float f) {
  union { float f; unsigned int u; } cv;
  cv.f = f;
  unsigned int u = cv.u;
  u += 0x7FFFu + ((u >> 16) & 1u);   // round-to-nearest-even
  return (unsigned short)(u >> 16);
}

// ---------------- Kernel 1: x fp32 -> bf16 (+ bias passthrough) -------------
__global__ __launch_bounds__(256) void cast_x_kernel(
    const float* __restrict__ x, unsigned short* __restrict__ xb,
    const float* __restrict__ bias, float* __restrict__ bias_out) {
  const int tid = blockIdx.x * 256 + threadIdx.x;   // one thread = 8 floats
  const float4* x4 = (const float4*)x;
  float4 v0 = x4[(size_t)tid * 2 + 0];
  float4 v1 = x4[(size_t)tid * 2 + 1];
  ushort8 o;
  o[0] = f32_to_bf16_rne(v0.x); o[1] = f32_to_bf16_rne(v0.y);
  o[2] = f32_to_bf16_rne(v0.z); o[3] = f32_to_bf16_rne(v0.w);
  o[4] = f32_to_bf16_rne(v1.x); o[5] = f32_to_bf16_rne(v1.y);
  o[6] = f32_to_bf16_rne(v1.z); o[7] = f32_to_bf16_rne(v1.w);
  *(ushort8*)(xb + (size_t)tid * 8) = o;
  if (tid < DOUT) bias_out[tid] = bias[tid];
}

// ---------------- Kernel 2: WeffT[n][k] = bf16(W[k][n] + sum_r A[k][r]B[r][n])
__global__ __launch_bounds__(256) void weff_kernel(
    const float* __restrict__ W, const float* __restrict__ A,
    const float* __restrict__ B, unsigned short* __restrict__ WT) {
  __shared__ float sB[RANK][64];
  __shared__ float sA[64][RANK];
  __shared__ unsigned short sT[64][65];   // [k][n], padded to break conflicts
  const int n0 = blockIdx.x * 64;
  const int k0 = blockIdx.y * 64;
  const int t = threadIdx.x;

  for (int idx = t; idx < RANK * 64; idx += 256) {
    int r = idx >> 6, c = idx & 63;
    sB[r][c] = B[(size_t)r * DOUT + n0 + c];
  }
  for (int idx = t; idx < 64 * RANK; idx += 256) {
    int i = idx >> 4, r = idx & 15;
    sA[i][r] = A[(size_t)(k0 + i) * RANK + r];
  }
  __syncthreads();

  const int c = t & 63;     // lane within wave
  const int sub = t >> 6;   // wave id 0..3
  #pragma unroll
  for (int p = 0; p < 16; ++p) {
    const int ki = p * 4 + sub;
    float acc = W[(size_t)(k0 + ki) * DOUT + n0 + c];
    #pragma unroll
    for (int r = 0; r < RANK; ++r) acc += sA[ki][r] * sB[r][c];
    sT[ki][c] = f32_to_bf16_rne(acc);
  }
  __syncthreads();
  #pragma unroll
  for (int p = 0; p < 16; ++p) {
    const int ni = p * 4 + sub;
    WT[(size_t)(n0 + ni) * DIN + k0 + c] = sT[c][ni];
  }
}

// ---------------- Kernel 3: C[m][n] = sum_k xb[m][k] * WT[n][k] (bf16 MFMA) --
// m97 structure: 128x128 tile, BK=32, 256 threads = 4 waves (2x2), each wave
// 4x4 tiles of v_mfma_f32_16x16x32_bf16. Staging via global_load_lds width 16.
// LDS layout (per operand): 128 rows x 4 chunks of 16 B. Chunk g of row r is
// stored at position g ^ ((r>>1)&3)  -> every 8 consecutive lanes of a
// ds_read_b128 cover all 8 four-bank groups exactly once (conflict-free).
// global_load_lds dest is forced to (base + lane*16), so the swizzle is
// applied by permuting the per-lane global SOURCE chunk instead.
#define BM 128
#define BN 128
#define BK 32

__global__ __launch_bounds__(256) void gemm_bt_kernel(
    const unsigned short* __restrict__ xb, const unsigned short* __restrict__ wt,
    float* __restrict__ out) {
  __shared__ unsigned short sA[BM * BK];  // swizzled [m][k-chunk] (8 KB)
  __shared__ unsigned short sB[BN * BK];  // swizzled [n][k-chunk] (8 KB)
  const int t = threadIdx.x;
  const int n0 = blockIdx.x * BN;
  const int m0 = blockIdx.y * BM;

  const int lane = t & 63;
  const int wv   = t >> 6;
  const int wr   = wv >> 1;     // wave row (0..1) -> 64 rows of C
  const int wc   = wv & 1;      // wave col (0..1) -> 64 cols of C
  const int quad = lane >> 4;   // 0..3
  const int lcol = lane & 15;

  // Staging: thread t fills LDS chunk t (row=t>>2, pos=t&3). Under the
  // swizzle, pos p of row r holds logical chunk g = p ^ ((r>>1)&3):
  const int srow = t >> 2;
  const int g    = (t & 3) ^ ((t >> 3) & 3);   // logical k-chunk to fetch
  const int scol = g * 8;                      // bf16 elements
  const unsigned short* gA0 = xb + (size_t)(m0 + srow) * DIN + scol;
  const unsigned short* gA1 = gA0 + (size_t)64 * DIN;
  const unsigned short* gB0 = wt + (size_t)(n0 + srow) * DIN + scol;
  const unsigned short* gB1 = gB0 + (size_t)64 * DIN;
  unsigned short* lA0 = (unsigned short*)sA + t * 8;
  unsigned short* lA1 = (unsigned short*)sA + (t + 256) * 8;
  unsigned short* lB0 = (unsigned short*)sB + t * 8;
  unsigned short* lB1 = (unsigned short*)sB + (t + 256) * 8;

  f32x4 acc[4][4] = {};

  // Fragment read offsets: row m = wr*64 + i*16 + lcol, logical chunk = quad,
  // stored at chunk position quad ^ ((m>>1)&3). The xor term is constant per
  // lane across i (i*16 and wr*64 don't affect bits 1..2 of m>>1 mod 4):
  const int xt   = (lcol >> 1) & 3;
  const int aoff = (wr * 64 + lcol) * BK + ((quad ^ xt) * 8);
  const int boff = (wc * 64 + lcol) * BK + ((quad ^ xt) * 8);

  for (int kt = 0; kt < DIN; kt += BK) {
    __builtin_amdgcn_global_load_lds(
        (const __attribute__((address_space(1))) void*)(gA0 + kt),
        (__attribute__((address_space(3))) void*)lA0, 16, 0, 0);
    __builtin_amdgcn_global_load_lds(
        (const __attribute__((address_space(1))) void*)(gA1 + kt),
        (__attribute__((address_space(3))) void*)lA1, 16, 0, 0);
    __builtin_amdgcn_global_load_lds(
        (const __attribute__((address_space(1))) void*)(gB0 + kt),
        (__attribute__((address_space(3))) void*)lB0, 16, 0, 0);
    __builtin_amdgcn_global_load_lds(
        (const __attribute__((address_space(1))) void*)(gB1 + kt),
        (__attribute__((address_space(3))) void*)lB1, 16, 0, 0);
    __syncthreads();   // drains vmcnt(0) before barrier -> staging visible

    bf16x8 a[4], b[4];
    #pragma unroll
    for (int i = 0; i < 4; ++i)
      a[i] = *(const bf16x8*)((const unsigned short*)sA + aoff + i * 16 * BK);
    #pragma unroll
    for (int j = 0; j < 4; ++j)
      b[j] = *(const bf16x8*)((const unsigned short*)sB + boff + j * 16 * BK);

    #pragma unroll
    for (int i = 0; i < 4; ++i)
      #pragma unroll
      for (int j = 0; j < 4; ++j)
        acc[i][j] = __builtin_amdgcn_mfma_f32_16x16x32_bf16(a[i], b[j], acc[i][j], 0, 0, 0);
    __syncthreads();   // protect LDS from next iteration's staging
  }

  // Epilogue: C/D layout col=lane&15, row=(lane>>4)*4+reg  [measured m89/m91]
  const int row_base = m0 + wr * 64 + quad * 4;
  const int col_base = n0 + wc * 64 + lcol;
  #pragma unroll
  for (int i = 0; i < 4; ++i)
    #pragma unroll
    for (int j = 0; j < 4; ++j)
      #pragma unroll
      for (int r = 0; r < 4; ++r)
        out[(size_t)(row_base + i * 16 + r) * DOUT + (col_base + j * 16)] =
            acc[i][j][r];
}

extern "C" void kernel_launch(void* const* d_in, const int* in_sizes, int n_in,
                              void* d_out, int out_size, void* d_ws, size_t ws_size,
                              hipStream_t stream) {
  const float* x    = (const float*)d_in[0];
  const float* W    = (const float*)d_in[1];
  const float* bias = (const float*)d_in[2];
  const float* A    = (const float*)d_in[3];
  const float* B    = (const float*)d_in[4];
  float* out      = (float*)d_out;
  float* bias_out = out + (size_t)SEQ * DOUT;   // second output, concatenated

  unsigned short* xb = (unsigned short*)d_ws;                   // 67,108,864 B
  unsigned short* wt = xb + (size_t)SEQ * DIN;                  // 33,554,432 B

  // 1) cast x -> bf16, copy bias to output tail
  cast_x_kernel<<<(SEQ * DIN) / (256 * 8), 256, 0, stream>>>(x, xb, bias, bias_out);
  // 2) WeffT = (W + A@B)^T in bf16
  weff_kernel<<<dim3(DOUT / 64, DIN / 64), 256, 0, stream>>>(W, A, B, wt);
  // 3) big bf16 GEMM: out = x @ Weff
  gemm_bt_kernel<<<dim3(DOUT / BN, SEQ / BM), 256, 0, stream>>>(xb, wt, out);
}

// Round 3
// 575.935 us; speedup vs baseline: 1.1703x; 1.1543x over previous
//
#include <hip/hip_runtime.h>
#include <cstdint>
#include <cstddef>

// out = x @ W + (x @ A) @ B ; second output = bias (passthrough)
// Strategy: fold LoRA into the weight (W_eff = W + A@B, transposed bf16),
// cast x to bf16, one big bf16 MFMA GEMM with fp32 accumulate.
// R3: BK=64 (halves the per-iteration vmcnt(0)+barrier drains that caused
// ~40% dead cycles in R2), new 8-chunk XOR swizzle, cast+weff fused into
// one prep dispatch.
// Workspace: [0,67108864) x_bf16 [8192][4096] ; [67108864,100663296) WeffT.

#define SEQ  8192
#define DIN  4096
#define DOUT 4096
#define RANK 16

typedef __attribute__((ext_vector_type(8))) __bf16 bf16x8;
typedef __attribute__((ext_vector_type(4))) float f32x4;
typedef __attribute__((ext_vector_type(8))) unsigned short ushort8;

#define CAST_BLOCKS ((SEQ * DIN) / (256 * 8))   // 16384
#define WEFF_BLOCKS ((DOUT / 64) * (DIN / 64))  // 4096

__device__ __forceinline__ unsigned short f32_to_bf16_rne(float f) {
  union { float f; unsigned int u; } cv;
  cv.f = f;
  unsigned int u = cv.u;
  u += 0x7FFFu + ((u >> 16) & 1u);
  return (unsigned short)(u >> 16);
}

// ---- Kernel 1 (fused prep): x->bf16 cast + bias copy, and WeffT build ----
__global__ __launch_bounds__(256) void prep_kernel(
    const float* __restrict__ x, unsigned short* __restrict__ xb,
    const float* __restrict__ bias, float* __restrict__ bias_out,
    const float* __restrict__ W, const float* __restrict__ A,
    const float* __restrict__ B, unsigned short* __restrict__ WT) {
  __shared__ float sBf[RANK][64];
  __shared__ float sAf[64][RANK];
  __shared__ unsigned short sT[64][65];   // padded transpose buffer
  const int bid = blockIdx.x;
  const int t = threadIdx.x;

  if (bid < CAST_BLOCKS) {
    const int tid = bid * 256 + t;        // one thread = 8 floats
    const float4* x4 = (const float4*)x;
    float4 v0 = x4[(size_t)tid * 2 + 0];
    float4 v1 = x4[(size_t)tid * 2 + 1];
    ushort8 o;
    o[0] = f32_to_bf16_rne(v0.x); o[1] = f32_to_bf16_rne(v0.y);
    o[2] = f32_to_bf16_rne(v0.z); o[3] = f32_to_bf16_rne(v0.w);
    o[4] = f32_to_bf16_rne(v1.x); o[5] = f32_to_bf16_rne(v1.y);
    o[6] = f32_to_bf16_rne(v1.z); o[7] = f32_to_bf16_rne(v1.w);
    *(ushort8*)(xb + (size_t)tid * 8) = o;
    if (tid < DOUT) bias_out[tid] = bias[tid];
    return;
  }

  // WeffT[n][k] = bf16(W[k][n] + sum_r A[k][r] B[r][n]); 64x64 tile
  const int b  = bid - CAST_BLOCKS;
  const int n0 = (b & 63) * 64;
  const int k0 = (b >> 6) * 64;

  for (int idx = t; idx < RANK * 64; idx += 256) {
    int r = idx >> 6, c = idx & 63;
    sBf[r][c] = B[(size_t)r * DOUT + n0 + c];
  }
  for (int idx = t; idx < 64 * RANK; idx += 256) {
    int i = idx >> 4, r = idx & 15;
    sAf[i][r] = A[(size_t)(k0 + i) * RANK + r];
  }
  __syncthreads();

  const int c   = t & 63;
  const int sub = t >> 6;
  #pragma unroll
  for (int p = 0; p < 16; ++p) {
    const int ki = p * 4 + sub;
    float acc = W[(size_t)(k0 + ki) * DOUT + n0 + c];
    #pragma unroll
    for (int r = 0; r < RANK; ++r) acc += sAf[ki][r] * sBf[r][c];
    sT[ki][c] = f32_to_bf16_rne(acc);
  }
  __syncthreads();
  #pragma unroll
  for (int p = 0; p < 16; ++p) {
    const int ni = p * 4 + sub;
    WT[(size_t)(n0 + ni) * DIN + k0 + c] = sT[c][ni];
  }
}

// ---- Kernel 2: C[m][n] = sum_k xb[m][k] * WT[n][k], bf16 MFMA, BK=64 ------
// LDS layout per operand: 128 rows x 8 chunks of 16 B (64 shorts/row, 16 KB).
// Chunk g of row r stored at position g ^ (r & 7):
//  - reader (ds_read_b128): row = lcol (+16i, +64wr: both ≡0 mod 8), logical
//    chunk = quad + 4*kk -> pos = chunk ^ (lcol & 7); every 8-lane window
//    covers all 8 bank groups (conflict-free, verified R2-style).
//  - stager: load slot j writes LDS at (j*4096B + lane*16) per the
//    wave-uniform-base constraint; it must hold slot s = j*256 + t, i.e.
//    row = j*32 + w*8 + (lane>>3), pos = lane&7 -> fetch logical chunk
//    g = (lane&7) ^ ((lane>>3)&7). Lanes 0..7 read one 128 B segment.
#define BM 128
#define BN 128
#define BK 64

__global__ __launch_bounds__(256) void gemm_bt_kernel(
    const unsigned short* __restrict__ xb, const unsigned short* __restrict__ wt,
    float* __restrict__ out) {
  __shared__ unsigned short sA[BM * BK];  // 16 KB
  __shared__ unsigned short sB[BN * BK];  // 16 KB
  const int t = threadIdx.x;
  const int n0 = blockIdx.x * BN;
  const int m0 = blockIdx.y * BM;

  const int lane = t & 63;
  const int w    = t >> 6;
  const int wr   = w >> 1;      // wave row -> 64 rows of C
  const int wc   = w & 1;       // wave col -> 64 cols of C
  const int quad = lane >> 4;
  const int lcol = lane & 15;

  // ---- staging addresses ----
  const int g     = (lane & 7) ^ ((lane >> 3) & 7);  // logical k-chunk
  const int rbase = w * 8 + (lane >> 3);             // + j*32 per slot
  const unsigned short* gA[4];
  const unsigned short* gB[4];
  #pragma unroll
  for (int j = 0; j < 4; ++j) {
    gA[j] = xb + (size_t)(m0 + rbase + j * 32) * DIN + g * 8;
    gB[j] = wt + (size_t)(n0 + rbase + j * 32) * DIN + g * 8;
  }
  unsigned short* lA[4];
  unsigned short* lB[4];
  #pragma unroll
  for (int j = 0; j < 4; ++j) {
    lA[j] = (unsigned short*)sA + (j * 256 + t) * 8;
    lB[j] = (unsigned short*)sB + (j * 256 + t) * 8;
  }

  f32x4 acc[4][4] = {};

  // ---- fragment read offsets (shorts) ----
  const int xorv = lcol & 7;
  const int arow = (wr * 64 + lcol) * BK;
  const int brow = (wc * 64 + lcol) * BK;

  for (int kt = 0; kt < DIN; kt += BK) {
    #pragma unroll
    for (int j = 0; j < 4; ++j)
      __builtin_amdgcn_global_load_lds(
          (const __attribute__((address_space(1))) void*)(gA[j] + kt),
          (__attribute__((address_space(3))) void*)lA[j], 16, 0, 0);
    #pragma unroll
    for (int j = 0; j < 4; ++j)
      __builtin_amdgcn_global_load_lds(
          (const __attribute__((address_space(1))) void*)(gB[j] + kt),
          (__attribute__((address_space(3))) void*)lB[j], 16, 0, 0);
    __syncthreads();   // drains vmcnt(0): staging visible

    #pragma unroll
    for (int kk = 0; kk < 2; ++kk) {
      const int cpos = ((quad + 4 * kk) ^ xorv) * 8;
      bf16x8 a[4], b[4];
      #pragma unroll
      for (int i = 0; i < 4; ++i)
        a[i] = *(const bf16x8*)((const unsigned short*)sA + arow + i * 16 * BK + cpos);
      #pragma unroll
      for (int j = 0; j < 4; ++j)
        b[j] = *(const bf16x8*)((const unsigned short*)sB + brow + j * 16 * BK + cpos);
      #pragma unroll
      for (int i = 0; i < 4; ++i)
        #pragma unroll
        for (int j = 0; j < 4; ++j)
          acc[i][j] = __builtin_amdgcn_mfma_f32_16x16x32_bf16(a[i], b[j], acc[i][j], 0, 0, 0);
    }
    __syncthreads();   // protect LDS before next staging
  }

  // Epilogue: C/D layout col=lane&15, row=(lane>>4)*4+reg [m89/m91]
  const int row_base = m0 + wr * 64 + quad * 4;
  const int col_base = n0 + wc * 64 + lcol;
  #pragma unroll
  for (int i = 0; i < 4; ++i)
    #pragma unroll
    for (int j = 0; j < 4; ++j)
      #pragma unroll
      for (int r = 0; r < 4; ++r)
        out[(size_t)(row_base + i * 16 + r) * DOUT + (col_base + j * 16)] =
            acc[i][j][r];
}

extern "C" void kernel_launch(void* const* d_in, const int* in_sizes, int n_in,
                              void* d_out, int out_size, void* d_ws, size_t ws_size,
                              hipStream_t stream) {
  const float* x    = (const float*)d_in[0];
  const float* W    = (const float*)d_in[1];
  const float* bias = (const float*)d_in[2];
  const float* A    = (const float*)d_in[3];
  const float* B    = (const float*)d_in[4];
  float* out      = (float*)d_out;
  float* bias_out = out + (size_t)SEQ * DOUT;

  unsigned short* xb = (unsigned short*)d_ws;
  unsigned short* wt = xb + (size_t)SEQ * DIN;

  prep_kernel<<<CAST_BLOCKS + WEFF_BLOCKS, 256, 0, stream>>>(
      x, xb, bias, bias_out, W, A, B, wt);
  gemm_bt_kernel<<<dim3(DOUT / BN, SEQ / BM), 256, 0, stream>>>(xb, wt, out);
}